// Round 1
// baseline (279.061 us; speedup 1.0000x reference)
//
#include <hip/hip_runtime.h>

#define Bsz 64
#define Nn  256
#define Ee  20   // atom embedding dim
#define Dd  25   // gaussian centers
#define Dp  28   // padded to float4 multiple

__device__ __forceinline__ float tanhfast(float x) {
    // safe at large |x|: e->inf => 1, e->0 => -1
    float e = __expf(2.0f * x);
    return 1.0f - 2.0f / (e + 1.0f);
}

__global__ __launch_bounds__(256) void dtnn_kernel(
    const int*   __restrict__ z,     // [B,N]
    const float* __restrict__ dist,  // [B,N,N]
    const float* __restrict__ emb,   // [N,E]
    const float* __restrict__ Vw,    // [E,45]
    const float* __restrict__ Vb,    // [E]
    const float* __restrict__ W1,    // [10,E]
    const float* __restrict__ b1,    // [10]
    const float* __restrict__ W2,    // [1,10]
    const float* __restrict__ b2,    // [1]
    float*       __restrict__ out)   // [B]
{
    __shared__ float sVc[Ee][Ee];   // Vw[:, :20]
    __shared__ float sVd[Ee][Dp];   // Vw[:, 20:45], zero-padded to 28

    const int tid = threadIdx.x;

    // cooperative LDS fill
    for (int idx = tid; idx < Ee * Ee; idx += 256) {
        int o = idx / Ee, f = idx % Ee;
        sVc[o][f] = Vw[o * 45 + f];
    }
    for (int idx = tid; idx < Ee * Dp; idx += 256) {
        int o = idx / Dp, k = idx % Dp;
        sVd[o][k] = (k < Dd) ? Vw[o * 45 + 20 + k] : 0.0f;
    }
    __syncthreads();

    const int lane = tid & 63;
    const int wave = tid >> 6;
    const int w    = blockIdx.x * 4 + wave;   // global (b,i) index
    const int b    = w >> 8;
    const int i    = w & 255;

    const int   zi    = z[b * Nn + i];
    const float maskv = (zi != 0) ? 1.0f : 0.0f;

    // cfeat (wave-uniform, broadcast loads)
    float cf[Ee];
    #pragma unroll
    for (int f = 0; f < Ee; ++f) cf[f] = emb[zi * Ee + f] * maskv;

    // A[o] = Vb[o] + Vw[:, :20] . cfeat  (constant over j)
    float A[Ee];
    #pragma unroll
    for (int o = 0; o < Ee; ++o) {
        float s = Vb[o];
        #pragma unroll
        for (int f = 0; f < Ee; ++f) s = fmaf(sVc[o][f], cf[f], s);
        A[o] = s;
    }

    // each lane: 4 neighbors via one float4 (coalesced, row is 256B-aligned)
    const float4 d4 = reinterpret_cast<const float4*>(
        dist + (size_t)(b * Nn + i) * Nn)[lane];
    const float dcomp[4] = {d4.x, d4.y, d4.z, d4.w};

    float acc[Ee];
    #pragma unroll
    for (int o = 0; o < Ee; ++o) acc[o] = 0.0f;

    // 2 passes x 2 neighbors each (keeps g register footprint at 56)
    #pragma unroll
    for (int pass = 0; pass < 2; ++pass) {
        float g0[Dp], g1[Dp];
        const float dj0 = dcomp[2 * pass + 0];
        const float dj1 = dcomp[2 * pass + 1];
        #pragma unroll
        for (int k = 0; k < Dd; ++k) {
            const float mu = 0.2f * (float)k;
            float u0 = dj0 - mu;
            float u1 = dj1 - mu;
            g0[k] = __expf(-2.0f * u0 * u0);
            g1[k] = __expf(-2.0f * u1 * u1);
        }
        #pragma unroll
        for (int k = Dd; k < Dp; ++k) { g0[k] = 0.0f; g1[k] = 0.0f; }

        #pragma unroll
        for (int o = 0; o < Ee; ++o) {
            const float4* wr = reinterpret_cast<const float4*>(sVd[o]);
            float s0 = A[o], s1 = A[o];
            #pragma unroll
            for (int q = 0; q < Dp / 4; ++q) {
                const float4 wv = wr[q];   // wave-uniform ds_read_b128 (broadcast)
                s0 = fmaf(wv.x, g0[4 * q + 0], s0);
                s0 = fmaf(wv.y, g0[4 * q + 1], s0);
                s0 = fmaf(wv.z, g0[4 * q + 2], s0);
                s0 = fmaf(wv.w, g0[4 * q + 3], s0);
                s1 = fmaf(wv.x, g1[4 * q + 0], s1);
                s1 = fmaf(wv.y, g1[4 * q + 1], s1);
                s1 = fmaf(wv.z, g1[4 * q + 2], s1);
                s1 = fmaf(wv.w, g1[4 * q + 3], s1);
            }
            acc[o] += tanhfast(s0) + tanhfast(s1);
        }
    }

    // butterfly reduce over 64 lanes (all lanes end with the sum)
    #pragma unroll
    for (int off = 32; off > 0; off >>= 1) {
        #pragma unroll
        for (int o = 0; o < Ee; ++o)
            acc[o] += __shfl_xor(acc[o], off, 64);
    }

    // epilogue (redundant across lanes; lane 0 commits)
    float th[Ee];
    #pragma unroll
    for (int o = 0; o < Ee; ++o)
        th[o] = tanhfast(cf[o] + acc[o] * maskv);

    float e = b2[0];
    #pragma unroll
    for (int p = 0; p < 10; ++p) {
        float h = b1[p];
        #pragma unroll
        for (int o = 0; o < Ee; ++o) h = fmaf(W1[p * Ee + o], th[o], h);
        e = fmaf(W2[p], h, e);
    }

    if (lane == 0) atomicAdd(&out[b], e);
}

extern "C" void kernel_launch(void* const* d_in, const int* in_sizes, int n_in,
                              void* d_out, int out_size, void* d_ws, size_t ws_size,
                              hipStream_t stream) {
    const int*   z    = (const int*)  d_in[0];
    const float* dist = (const float*)d_in[1];
    const float* emb  = (const float*)d_in[2];
    const float* Vw   = (const float*)d_in[3];
    const float* Vb   = (const float*)d_in[4];
    const float* W1   = (const float*)d_in[5];
    const float* b1   = (const float*)d_in[6];
    const float* W2   = (const float*)d_in[7];
    const float* b2   = (const float*)d_in[8];
    float* out = (float*)d_out;

    hipMemsetAsync(out, 0, Bsz * sizeof(float), stream);

    // one wave per (b,i): B*N = 16384 waves, 4 waves/block -> 4096 blocks
    dtnn_kernel<<<Bsz * Nn / 4, 256, 0, stream>>>(
        z, dist, emb, Vw, Vb, W1, b1, W2, b2, out);
}

// Round 2
// 239.883 us; speedup vs baseline: 1.1633x; 1.1633x over previous
//
#include <hip/hip_runtime.h>

#define Bsz 64
#define Nn  256
#define Ee  20   // atom embedding dim
#define Dd  25   // gaussian centers

using short8  = __attribute__((ext_vector_type(8))) short;  // 8 bf16 (4 VGPRs)
using floatx4 = __attribute__((ext_vector_type(4))) float;  // 4 fp32 acc

__device__ __forceinline__ short f2bf(float x) {            // RNE fp32->bf16
    unsigned u = __float_as_uint(x);
    unsigned r = (u + 0x7FFFu + ((u >> 16) & 1u)) >> 16;
    return (short)r;
}
__device__ __forceinline__ float bf2f(short h) {
    return __uint_as_float(((unsigned)(unsigned short)h) << 16);
}
__device__ __forceinline__ float tanhfast(float x) {
    // safe at large |x|: e->inf => 1, e->0 => -1
    float e = __expf(2.0f * x);
    return 1.0f - 2.0f / (e + 1.0f);
}

__global__ __launch_bounds__(256) void dtnn_kernel(
    const int*   __restrict__ z,     // [B,N]
    const float* __restrict__ dist,  // [B,N,N]
    const float* __restrict__ emb,   // [N,E]
    const float* __restrict__ Vw,    // [E,45]
    const float* __restrict__ Vb,    // [E]
    const float* __restrict__ W1,    // [10,E]
    const float* __restrict__ b1,    // [10]
    const float* __restrict__ W2,    // [1,10]
    const float* __restrict__ b2,    // [1]
    float*       __restrict__ out)   // [B]
{
    const int tid  = threadIdx.x;
    const int lane = tid & 63;
    const int wv   = blockIdx.x * 4 + (tid >> 6);  // global (b,i)
    const int b    = wv >> 8;
    const int i    = wv & 255;

    const int c16  = lane & 15;   // MFMA: A-row m / D-col n index
    const int quad = lane >> 4;
    const int k0   = quad * 8;    // my K-slice start (RBF index)

    // ---- B-fragments: weights Vw[:,20:45] in bf16 hi/lo, resident in VGPRs.
    // B[k][n]: lane holds n = c16 (+16 for ntile 1), k = k0+jj. Pad k>=25, o>=20 with 0.
    short8 whi[2], wlo[2];
    #pragma unroll
    for (int nt = 0; nt < 2; ++nt) {
        const int o = nt * 16 + c16;
        #pragma unroll
        for (int jj = 0; jj < 8; ++jj) {
            const int k = k0 + jj;
            float wvf = (o < Ee && k < Dd) ? Vw[o * 45 + 20 + k] : 0.0f;
            short h = f2bf(wvf);
            whi[nt][jj] = h;
            wlo[nt][jj] = f2bf(wvf - bf2f(h));
        }
    }

    const int   zi    = z[b * Nn + i];
    const float maskv = (zi != 0) ? 1.0f : 0.0f;

    // ---- per-lane bias A[o] = Vb[o] + mask * (Vw[:, :20] . emb_row), and cfeat[o]
    float Abias[2], cfo[2];
    #pragma unroll
    for (int nt = 0; nt < 2; ++nt) {
        const int o = nt * 16 + c16;
        float s = 0.0f, cfv = 0.0f;
        if (o < Ee) {
            float dot = 0.0f;
            #pragma unroll
            for (int f = 0; f < Ee; ++f)
                dot = fmaf(Vw[o * 45 + f], emb[zi * Ee + f], dot);
            s   = Vb[o] + maskv * dot;
            cfv = maskv * emb[zi * Ee + o];
        }
        Abias[nt] = s;
        cfo[nt]   = cfv;
    }

    // ---- main loop: 16 j-tiles of 16 neighbors, weights never leave registers
    const float* drow = dist + (size_t)(b * Nn + i) * Nn;
    const float  mu0  = 0.2f * (float)k0;
    const float  CR   = 0.8521437889662113f;  // exp(-0.16)

    float part0 = 0.0f, part1 = 0.0f;

    #pragma unroll 4
    for (int t = 0; t < 16; ++t) {
        // A-fragment: g[k] = exp(-2(d-mu_k)^2) for my j = t*16+c16, k = k0..k0+7
        // recurrence: g[k+1] = g[k]*r_k, r_{k+1} = r_k*exp(-0.16)
        const float d = drow[t * 16 + c16];
        const float u = d - mu0;
        float g = __expf(-2.0f * u * u);
        float r = __expf(0.8f * u - 0.08f);
        short8 ghi, glo;
        #pragma unroll
        for (int jj = 0; jj < 8; ++jj) {
            if (jj) { g *= r; r *= CR; }
            short h = f2bf(g);
            ghi[jj] = h;
            glo[jj] = f2bf(g - bf2f(h));
        }

        floatx4 acc0 = {Abias[0], Abias[0], Abias[0], Abias[0]};
        floatx4 acc1 = {Abias[1], Abias[1], Abias[1], Abias[1]};
        // split-precision product: hi*hi + lo*hi + hi*lo  (~fp32 accurate)
        acc0 = __builtin_amdgcn_mfma_f32_16x16x32_bf16(ghi, whi[0], acc0, 0, 0, 0);
        acc0 = __builtin_amdgcn_mfma_f32_16x16x32_bf16(glo, whi[0], acc0, 0, 0, 0);
        acc0 = __builtin_amdgcn_mfma_f32_16x16x32_bf16(ghi, wlo[0], acc0, 0, 0, 0);
        acc1 = __builtin_amdgcn_mfma_f32_16x16x32_bf16(ghi, whi[1], acc1, 0, 0, 0);
        acc1 = __builtin_amdgcn_mfma_f32_16x16x32_bf16(glo, whi[1], acc1, 0, 0, 0);
        acc1 = __builtin_amdgcn_mfma_f32_16x16x32_bf16(ghi, wlo[1], acc1, 0, 0, 0);

        // D[m=quad*4+reg][n=c16]; tanh then sum over the j's (rows) I hold
        #pragma unroll
        for (int reg = 0; reg < 4; ++reg) {
            part0 += tanhfast(acc0[reg]);
            part1 += tanhfast(acc1[reg]);
        }
    }

    // sum over quads (rows j are spread across quads): lanes l, l+16, l+32, l+48
    part0 += __shfl_xor(part0, 16, 64);
    part0 += __shfl_xor(part0, 32, 64);
    part1 += __shfl_xor(part1, 16, 64);
    part1 += __shfl_xor(part1, 32, 64);

    // epilogue: c = cfeat + mask*agg; th = tanh(c); e = C0 + sum_o u[o]*th[o]
    // (top MLP is linear after the tanh -> fold W1,W2 into u)
    float e = 0.0f;
    #pragma unroll
    for (int nt = 0; nt < 2; ++nt) {
        const int o = nt * 16 + c16;
        const float agg = (nt == 0) ? part0 : part1;
        const float th  = tanhfast(cfo[nt] + maskv * agg);
        float uo = 0.0f;
        if (o < Ee) {
            #pragma unroll
            for (int p = 0; p < 10; ++p)
                uo = fmaf(W2[p], W1[p * Ee + o], uo);
        }
        e = fmaf(th, uo, e);
    }
    // reduce over the 16 columns (quads hold duplicates)
    e += __shfl_xor(e, 1, 64);
    e += __shfl_xor(e, 2, 64);
    e += __shfl_xor(e, 4, 64);
    e += __shfl_xor(e, 8, 64);

    if (lane == 0) {
        float C0 = b2[0];
        #pragma unroll
        for (int p = 0; p < 10; ++p) C0 = fmaf(W2[p], b1[p], C0);
        atomicAdd(&out[b], e + C0);
    }
}

extern "C" void kernel_launch(void* const* d_in, const int* in_sizes, int n_in,
                              void* d_out, int out_size, void* d_ws, size_t ws_size,
                              hipStream_t stream) {
    const int*   z    = (const int*)  d_in[0];
    const float* dist = (const float*)d_in[1];
    const float* emb  = (const float*)d_in[2];
    const float* Vw   = (const float*)d_in[3];
    const float* Vb   = (const float*)d_in[4];
    const float* W1   = (const float*)d_in[5];
    const float* b1   = (const float*)d_in[6];
    const float* W2   = (const float*)d_in[7];
    const float* b2   = (const float*)d_in[8];
    float* out = (float*)d_out;

    hipMemsetAsync(out, 0, Bsz * sizeof(float), stream);

    // one wave per (b,i): B*N = 16384 waves, 4 waves/block -> 4096 blocks
    dtnn_kernel<<<Bsz * Nn / 4, 256, 0, stream>>>(
        z, dist, emb, Vw, Vb, W1, b1, W2, b2, out);
}

// Round 3
// 228.137 us; speedup vs baseline: 1.2232x; 1.0515x over previous
//
#include <hip/hip_runtime.h>

#define Bsz 64
#define Nn  256
#define Ee  20   // atom embedding dim
#define Dd  25   // gaussian centers

using short8  = __attribute__((ext_vector_type(8))) short;  // 8 bf16 (4 VGPRs)
using floatx4 = __attribute__((ext_vector_type(4))) float;  // 4 fp32 acc

#if __has_builtin(__builtin_amdgcn_exp2f)
#define EXP2F(x) __builtin_amdgcn_exp2f(x)
#else
#define EXP2F(x) __expf(0.6931471805599453f * (x))
#endif
#if __has_builtin(__builtin_amdgcn_rcpf)
#define RCPF(x) __builtin_amdgcn_rcpf(x)
#else
#define RCPF(x) (1.0f / (x))
#endif

__device__ __forceinline__ short f2bf(float x) {            // RNE fp32->bf16
    unsigned u = __float_as_uint(x);
    unsigned r = (u + 0x7FFFu + ((u >> 16) & 1u)) >> 16;
    return (short)r;
}
__device__ __forceinline__ float bf2f(short h) {
    return __uint_as_float(((unsigned)(unsigned short)h) << 16);
}
__device__ __forceinline__ float tanhfast(float x) {
    float e = __expf(2.0f * x);
    return 1.0f - 2.0f / (e + 1.0f);
}

__global__ __launch_bounds__(256) void dtnn_kernel(
    const int*   __restrict__ z,     // [B,N]
    const float* __restrict__ dist,  // [B,N,N]
    const float* __restrict__ emb,   // [N,E]
    const float* __restrict__ Vw,    // [E,45]
    const float* __restrict__ Vb,    // [E]
    const float* __restrict__ W1,    // [10,E]
    const float* __restrict__ b1,    // [10]
    const float* __restrict__ W2,    // [1,10]
    const float* __restrict__ b2,    // [1]
    float*       __restrict__ out)   // [B]
{
    const int tid  = threadIdx.x;
    const int lane = tid & 63;
    const int wv   = blockIdx.x * 4 + (tid >> 6);  // global (b,i)
    const int b    = wv >> 8;
    const int i    = wv & 255;

    const int c16  = lane & 15;   // MFMA: A-row m / D-col n index
    const int quad = lane >> 4;
    const int k0   = quad * 8;    // my K-slice start (RBF index)

    const float Kc = 2.8853900817779268f;   // 2*log2(e), folded into w & bias

    // ---- up-front dist row: 4 coalesced b32 loads, lane l holds d[l + 64c]
    const float* drow = dist + (size_t)(b * Nn + i) * Nn;
    const float d0 = drow[lane];
    const float d1 = drow[lane + 64];
    const float d2 = drow[lane + 128];
    const float d3 = drow[lane + 192];

    // ---- B-fragments: Kc*Vw[:,20:45] in bf16 hi/lo, resident in VGPRs
    short8 whiK[2], wloK[2];
    #pragma unroll
    for (int nt = 0; nt < 2; ++nt) {
        const int o = nt * 16 + c16;
        #pragma unroll
        for (int jj = 0; jj < 8; ++jj) {
            const int k = k0 + jj;
            float wvf = (o < Ee && k < Dd) ? Kc * Vw[o * 45 + 20 + k] : 0.0f;
            short h = f2bf(wvf);
            whiK[nt][jj] = h;
            wloK[nt][jj] = f2bf(wvf - bf2f(h));
        }
    }

    const int   zi    = z[b * Nn + i];
    const float maskv = (zi != 0) ? 1.0f : 0.0f;

    // ---- per-lane scaled bias AbK[o] = Kc*(Vb[o] + mask*(Vw[:, :20].emb)), cfeat
    float AbK[2], cfo[2];
    #pragma unroll
    for (int nt = 0; nt < 2; ++nt) {
        const int o = nt * 16 + c16;
        float s = 0.0f, cfv = 0.0f;
        if (o < Ee) {
            float dot = 0.0f;
            #pragma unroll
            for (int f = 0; f < Ee; ++f)
                dot = fmaf(Vw[o * 45 + f], emb[zi * Ee + f], dot);
            s   = Kc * (Vb[o] + maskv * dot);
            cfv = maskv * emb[zi * Ee + o];
        }
        AbK[nt] = s;
        cfo[nt] = cfv;
    }

    // ---- main loop: 16 j-tiles; tanh-sum as  sum tanh = 256 - 2*sum sigma
    const float mu0 = 0.2f * (float)k0;
    const float CR  = 0.8521437889662113f;   // exp(-0.16)

    float R0 = 0.0f, R1 = 0.0f;

    #pragma unroll 4
    for (int t = 0; t < 16; ++t) {
        // d for my row j = t*16 + c16 via register bpermute (no global load)
        const int srcLane = 16 * (t & 3) + c16;
        float s01 = (t & 4) ? d1 : d0;
        float s23 = (t & 4) ? d3 : d2;
        float dv  = (t & 8) ? s23 : s01;
        const float d = __shfl(dv, srcLane, 64);

        // RBF recurrence in exp2 domain: g=exp(-2u^2), r=exp(0.8u-0.08)
        const float u = d - mu0;
        float g = EXP2F(-2.8853900817779268f * (u * u));
        float r = EXP2F(fmaf(1.1541560327111707f, u, -0.11541560327111707f));
        short8 ghi;
        #pragma unroll
        for (int jj = 0; jj < 8; ++jj) {
            if (jj) { g *= r; r *= CR; }
            ghi[jj] = f2bf(g);
        }

        floatx4 acc0 = {AbK[0], AbK[0], AbK[0], AbK[0]};
        floatx4 acc1 = {AbK[1], AbK[1], AbK[1], AbK[1]};
        // split-precision weights: g*whi + g*wlo  (~fp32-accurate product)
        acc0 = __builtin_amdgcn_mfma_f32_16x16x32_bf16(ghi, whiK[0], acc0, 0, 0, 0);
        acc0 = __builtin_amdgcn_mfma_f32_16x16x32_bf16(ghi, wloK[0], acc0, 0, 0, 0);
        acc1 = __builtin_amdgcn_mfma_f32_16x16x32_bf16(ghi, whiK[1], acc1, 0, 0, 0);
        acc1 = __builtin_amdgcn_mfma_f32_16x16x32_bf16(ghi, wloK[1], acc1, 0, 0, 0);

        // acc = 2*log2(e)*s  ->  sigma = 1/(2^acc + 1); tanh = 1 - 2*sigma
        #pragma unroll
        for (int reg = 0; reg < 4; ++reg) {
            R0 += RCPF(EXP2F(acc0[reg]) + 1.0f);
            R1 += RCPF(EXP2F(acc1[reg]) + 1.0f);
        }
    }

    // reduce sigma-sums over quads (rows j spread across quads)
    R0 += __shfl_xor(R0, 16, 64);
    R0 += __shfl_xor(R0, 32, 64);
    R1 += __shfl_xor(R1, 16, 64);
    R1 += __shfl_xor(R1, 32, 64);
    const float agg0 = 256.0f - 2.0f * R0;
    const float agg1 = 256.0f - 2.0f * R1;

    // epilogue: th = tanh(cfeat + mask*agg); e = C0 + sum_o u[o]*th[o]
    float e = 0.0f;
    #pragma unroll
    for (int nt = 0; nt < 2; ++nt) {
        const int o   = nt * 16 + c16;
        const float agg = (nt == 0) ? agg0 : agg1;
        const float th  = tanhfast(cfo[nt] + maskv * agg);
        float uo = 0.0f;
        if (o < Ee) {
            #pragma unroll
            for (int p = 0; p < 10; ++p)
                uo = fmaf(W2[p], W1[p * Ee + o], uo);
        }
        e = fmaf(th, uo, e);
    }
    // reduce over the 16 columns (quads hold duplicates)
    e += __shfl_xor(e, 1, 64);
    e += __shfl_xor(e, 2, 64);
    e += __shfl_xor(e, 4, 64);
    e += __shfl_xor(e, 8, 64);

    if (lane == 0) {
        float C0 = b2[0];
        #pragma unroll
        for (int p = 0; p < 10; ++p) C0 = fmaf(W2[p], b1[p], C0);
        atomicAdd(&out[b], e + C0);
    }
}

extern "C" void kernel_launch(void* const* d_in, const int* in_sizes, int n_in,
                              void* d_out, int out_size, void* d_ws, size_t ws_size,
                              hipStream_t stream) {
    const int*   z    = (const int*)  d_in[0];
    const float* dist = (const float*)d_in[1];
    const float* emb  = (const float*)d_in[2];
    const float* Vw   = (const float*)d_in[3];
    const float* Vb   = (const float*)d_in[4];
    const float* W1   = (const float*)d_in[5];
    const float* b1   = (const float*)d_in[6];
    const float* W2   = (const float*)d_in[7];
    const float* b2   = (const float*)d_in[8];
    float* out = (float*)d_out;

    hipMemsetAsync(out, 0, Bsz * sizeof(float), stream);

    // one wave per (b,i): B*N = 16384 waves, 4 waves/block -> 4096 blocks
    dtnn_kernel<<<Bsz * Nn / 4, 256, 0, stream>>>(
        z, dist, emb, Vw, Vb, W1, b1, W2, b2, out);
}